// Round 6
// baseline (85.686 us; speedup 1.0000x reference)
//
#include <hip/hip_runtime.h>
#include <hip/hip_bf16.h>
#include <math.h>

typedef float  f32x4 __attribute__((ext_vector_type(4)));
typedef short  s16x8 __attribute__((ext_vector_type(8)));
typedef unsigned int u32x2 __attribute__((ext_vector_type(2)));
typedef unsigned int u32x4 __attribute__((ext_vector_type(4)));

constexpr int kNRays = 16384;
constexpr int kTableSize = 1 << 19;
constexpr int kOffDepth   = kNRays * 3;
constexpr int kOffAcc     = kOffDepth + kNRays;
constexpr int kOffWeights = kOffAcc + kNRays;

// Pre-staged A-fragment regions in d_ws (ushort offsets). All KT=2 except g0.
constexpr int kWg0 = 0;      // 32x64  KT=1 MT=4 -> 2048
constexpr int kWg1 = 2048;   // 64x64  KT=2 MT=4 -> 4096
constexpr int kWd  = 6144;   // 64x16  KT=2 MT=1 -> 1024 (dperm)
constexpr int kWc0 = 7168;   // 24x64 staged as 64x64 KT=2 (rows 24..63 zero) -> 4096
constexpr int kWc1 = 11264;  // 64x64  -> 4096
constexpr int kWc2 = 15360;  // 64x64  -> 4096
constexpr int kWch = 19456;  // 64x3   KT=2 MT=1 -> 1024
constexpr int kWsTotal = 20480;

__device__ __forceinline__ ushort f2bf(float x) {
    unsigned u = __float_as_uint(x);
    return (ushort)((u + 0x7FFFu + ((u >> 16) & 1u)) >> 16);
}
__device__ __forceinline__ unsigned pk2(float lo, float hi) {
    __hip_bfloat162 h = __float22bfloat162_rn(float2{lo, hi});
    return *reinterpret_cast<unsigned*>(&h);   // v_cvt_pk_bf16_f32
}
__device__ __forceinline__ float sel4(float v0, float v1, float v2, float v3, int s) {
    float a = (s & 1) ? v1 : v0;
    float b = (s & 1) ? v3 : v2;
    return (s & 2) ? b : a;
}
__device__ __forceinline__ float wave_sum(float v) {
#pragma unroll
    for (int off = 32; off > 0; off >>= 1) v += __shfl_xor(v, off, 64);
    return v;
}

// One-time weight staging: W (f32 [FIN][FOUT]) -> bf16 A-fragments in ws.
__global__ __launch_bounds__(256) void prep_weights(
    const float* __restrict__ Wg0, const float* __restrict__ Wg1,
    const float* __restrict__ Wd,  const float* __restrict__ Wc0,
    const float* __restrict__ Wc1, const float* __restrict__ Wc2,
    const float* __restrict__ Wch, ushort* __restrict__ ws)
{
    const int i = blockIdx.x * 256 + threadIdx.x;
    if (i >= kWsTotal) return;
    const float* W; int FIN, FOUT, KT, base; bool dperm = false;
    if (i < kWg1)      { W = Wg0; FIN = 32; FOUT = 64; KT = 1; base = kWg0; }
    else if (i < kWd)  { W = Wg1; FIN = 64; FOUT = 64; KT = 2; base = kWg1; }
    else if (i < kWc0) { W = Wd;  FIN = 64; FOUT = 16; KT = 2; base = kWd; dperm = true; }
    else if (i < kWc1) { W = Wc0; FIN = 24; FOUT = 64; KT = 2; base = kWc0; }
    else if (i < kWc2) { W = Wc1; FIN = 64; FOUT = 64; KT = 2; base = kWc1; }
    else if (i < kWch) { W = Wc2; FIN = 64; FOUT = 64; KT = 2; base = kWc2; }
    else               { W = Wch; FIN = 64; FOUT = 3;  KT = 2; base = kWch; }
    const int r = i - base;
    const int e = r & 7, l = (r >> 3) & 63, t = r >> 9;
    const int kt = t % KT, mt = t / KT;
    const int k = kt * 32 + ((l >> 4) << 3) + e;
    int j = mt * 16 + (l & 15);
    if (dperm) j = (j == 15) ? 0 : j + 1;   // geo[0] -> row 15, geo[1..15] -> rows 0..14
    float w = 0.0f;
    if (k < FIN && j < FOUT) w = W[k * FOUT + j];
    ws[i] = f2bf(w);
}

// Small (16-col-out) layer: MT=1, KT=2, returns acc tiles.
__device__ __forceinline__ void layer16(const ushort* Xw, const ushort* __restrict__ Aws,
                                        int c16, int g, int lane, f32x4 acc[4]) {
    const s16x8 A0 = *(const s16x8*)&Aws[(0 * 64 + lane) * 8];
    const s16x8 A1 = *(const s16x8*)&Aws[(1 * 64 + lane) * 8];
#pragma unroll
    for (int nt = 0; nt < 4; ++nt) {
        const int col = nt * 16 + c16;
        const s16x8 B0 = *(const s16x8*)&Xw[col * 64 + 8 * ((0 * 4 + g) ^ (c16 & 7))];
        acc[nt] = __builtin_amdgcn_mfma_f32_16x16x32_bf16(A0, B0, acc[nt], 0, 0, 0);
        const s16x8 B1 = *(const s16x8*)&Xw[col * 64 + 8 * ((1 * 4 + g) ^ (c16 & 7))];
        acc[nt] = __builtin_amdgcn_mfma_f32_16x16x32_bf16(A1, B1, acc[nt], 0, 0, 0);
    }
}

__global__ __launch_bounds__(256, 4) void nerf_mfma_kernel(
    const float* __restrict__ rays_o, const float* __restrict__ rays_d,
    const float* __restrict__ tables, const ushort* __restrict__ ws,
    const float* __restrict__ bg0, const float* __restrict__ bg1,
    const float* __restrict__ bd,  const float* __restrict__ bc0,
    const float* __restrict__ bc1, const float* __restrict__ bc2,
    const float* __restrict__ bch, float* __restrict__ out)
{
    __shared__ __align__(16) ushort Xs[4 * 4096];
    const int tid  = threadIdx.x;
    const int wid  = tid >> 6;
    const int lane = tid & 63;
    const int c16  = lane & 15;
    const int g    = lane >> 4;
    const int ray  = blockIdx.x * 4 + wid;
    ushort* Xw = Xs + wid * 4096;

    const float ox = rays_o[ray * 3 + 0], oy = rays_o[ray * 3 + 1], oz = rays_o[ray * 3 + 2];
    const float dx = rays_d[ray * 3 + 0], dy = rays_d[ray * 3 + 1], dz = rays_d[ray * 3 + 2];

    const float step = 1.0f / 63.0f;
    const float z  = 0.1f + 1.4f * ((float)lane * step);
    const float zn = 0.1f + 1.4f * ((float)(lane + 1) * step);

    // per-level table base pointers for this lane's 4 levels (lv = g*4+j)
    const float2* lvb[4];
#pragma unroll
    for (int j = 0; j < 4; ++j)
        lvb[j] = (const float2*)tables + ((size_t)(g * 4 + j) << 19);

    // ---- input-layer B fragments straight from the hash gather ----
    // lane (g,c16), tile nt: sample s = nt*16+c16, levels g*4+j
    const float tc = (float)c16 * step;
    s16x8 B0f[4];
#pragma unroll
    for (int nt = 0; nt < 4; ++nt) {
        const float ts = tc + (float)nt * (16.0f / 63.0f);
        const float zs = fmaf(1.4f, ts, 0.1f);
        const float px = fmaf(dx, zs, ox), py = fmaf(dy, zs, oy), pz = fmaf(dz, zs, oz);
        u32x4 val;
#pragma unroll
        for (int j = 0; j < 4; ++j) {
            const int lv = g * 4 + j;
            const float res = (float)(32 << lv);
            const float rm1 = res - 1.0f;
            const float h = 0.5f * rm1;
            const float sx = __builtin_amdgcn_fmed3f(fmaf(px, h, h), 0.f, rm1);
            const float sy = __builtin_amdgcn_fmed3f(fmaf(py, h, h), 0.f, rm1);
            const float sz = __builtin_amdgcn_fmed3f(fmaf(pz, h, h), 0.f, rm1);
            const float idxf = fmaf(sx, res * res, fmaf(sy, res, sz));
            const float szm1 = (lv == 0) ? 32767.f : (lv == 1) ? 262143.f : 524287.f;
            const int idx = (int)fminf(idxf, szm1);
            const float2 f2 = lvb[j][idx];
            val[j] = pk2(f2.x, f2.y);
        }
        B0f[nt] = *(const s16x8*)&val;
    }

    // ---- g0: 32 -> 64, relu (B direct from gather), mt rolled ----
#pragma unroll 1
    for (int mt = 0; mt < 4; ++mt) {
        const s16x8 A0 = *(const s16x8*)&ws[kWg0 + (mt * 64 + lane) * 8];
        const f32x4 b = *(const f32x4*)(bg0 + mt * 16 + g * 4);
        f32x4 acc[4];
#pragma unroll
        for (int nt = 0; nt < 4; ++nt) {
            acc[nt] = b;
            acc[nt] = __builtin_amdgcn_mfma_f32_16x16x32_bf16(A0, B0f[nt], acc[nt], 0, 0, 0);
        }
#pragma unroll
        for (int nt = 0; nt < 4; ++nt) {
            const int col = nt * 16 + c16;
            const float x0 = fmaxf(acc[nt].x, 0.f), x1 = fmaxf(acc[nt].y, 0.f);
            const float x2 = fmaxf(acc[nt].z, 0.f), x3 = fmaxf(acc[nt].w, 0.f);
            const int a = col * 64 + 8 * ((2 * mt + (g >> 1)) ^ (c16 & 7)) + 4 * (g & 1);
            *(u32x2*)&Xw[a] = (u32x2){ pk2(x0, x1), pk2(x2, x3) };
        }
    }

    // ---- unified 64->64 layers: g1, c0, c1, c2 (one code copy) ----
    float lgit = 0.f;
#pragma unroll 1
    for (int li = 0; li < 4; ++li) {
        const ushort* Aws = ws + ((li == 0) ? kWg1 : kWc0 + (li - 1) * 4096);
        const float* bp = (li == 0) ? bg1 : (li == 1) ? bc0 : (li == 2) ? bc1 : bc2;
        s16x8 B[2][4];
#pragma unroll
        for (int kt = 0; kt < 2; ++kt)
#pragma unroll
            for (int nt = 0; nt < 4; ++nt) {
                const int col = nt * 16 + c16;
                B[kt][nt] = *(const s16x8*)&Xw[col * 64 + 8 * ((kt * 4 + g) ^ (c16 & 7))];
            }
#pragma unroll 1
        for (int mt = 0; mt < 4; ++mt) {
            const s16x8 A0 = *(const s16x8*)&Aws[((mt * 2 + 0) * 64 + lane) * 8];
            const s16x8 A1 = *(const s16x8*)&Aws[((mt * 2 + 1) * 64 + lane) * 8];
            const f32x4 b = *(const f32x4*)(bp + mt * 16 + g * 4);
            f32x4 acc[4];
#pragma unroll
            for (int nt = 0; nt < 4; ++nt) {
                acc[nt] = b;
                acc[nt] = __builtin_amdgcn_mfma_f32_16x16x32_bf16(A0, B[0][nt], acc[nt], 0, 0, 0);
                acc[nt] = __builtin_amdgcn_mfma_f32_16x16x32_bf16(A1, B[1][nt], acc[nt], 0, 0, 0);
            }
#pragma unroll
            for (int nt = 0; nt < 4; ++nt) {
                const int col = nt * 16 + c16;
                const float x0 = fmaxf(acc[nt].x, 0.f), x1 = fmaxf(acc[nt].y, 0.f);
                const float x2 = fmaxf(acc[nt].z, 0.f), x3 = fmaxf(acc[nt].w, 0.f);
                const int a = col * 64 + 8 * ((2 * mt + (g >> 1)) ^ (c16 & 7)) + 4 * (g & 1);
                *(u32x2*)&Xw[a] = (u32x2){ pk2(x0, x1), pk2(x2, x3) };
            }
        }
        if (li == 0) {
            // ---- d: 64 -> 16 (cols rotated; row 15 = geo[0]) off g1 acts ----
            f32x4 accd[4];
            {
                const float db0 = bd[g * 4 + 1];
                const float db1 = bd[g * 4 + 2];
                const float db2 = bd[g * 4 + 3];
                const int i3 = (g == 3) ? 0 : g * 4 + 4;
                const float db3 = bd[i3];
                const f32x4 b = { db0, db1, db2, db3 };
#pragma unroll
                for (int nt = 0; nt < 4; ++nt) accd[nt] = b;
            }
            layer16(Xw, ws + kWd, c16, g, lane, accd);
            lgit = sel4(__shfl(accd[0].w, 48 + c16, 64),
                        __shfl(accd[1].w, 48 + c16, 64),
                        __shfl(accd[2].w, 48 + c16, 64),
                        __shfl(accd[3].w, 48 + c16, 64), g);
            // store c_in rows 0..15 (row 15 junk, fixed below)
#pragma unroll
            for (int nt = 0; nt < 4; ++nt) {
                const int col = nt * 16 + c16;
                const int a = col * 64 + 8 * ((g >> 1) ^ (c16 & 7)) + 4 * (g & 1);
                *(u32x2*)&Xw[a] = (u32x2){ pk2(accd[nt].x, accd[nt].y),
                                           pk2(accd[nt].z, accd[nt].w) };
            }
            Xw[lane * 64 + 8 * (1 ^ (lane & 7)) + 7] = 0x3F00; // row 15 := bf16(0.5)
            {   // SH rows 16..23 (per-ray uniform); rows 24..63 = stale g1 acts x zero weights
                u32x4 w = { pk2(dx, dy), pk2(dz, dx * dy), pk2(dx * dz, dy * dz),
                            pk2(dx * dx - dy * dy, 3.f * dz * dz - 1.f) };
                *(u32x4*)&Xw[lane * 64 + 8 * (2 ^ (lane & 7))] = w;
            }
        }
    }

    // ---- ch: 64 -> 3 ----
    f32x4 accc[4];
    {
        const float cb0 = bch[0], cb1 = bch[1], cb2 = bch[2];
        const f32x4 b = (g == 0) ? (f32x4){ cb0, cb1, cb2, 0.f } : (f32x4){ 0.f, 0.f, 0.f, 0.f };
#pragma unroll
        for (int nt = 0; nt < 4; ++nt) accc[nt] = b;
    }
    layer16(Xw, ws + kWch, c16, g, lane, accc);
    const float lr = sel4(__shfl(accc[0].x, c16, 64), __shfl(accc[1].x, c16, 64),
                          __shfl(accc[2].x, c16, 64), __shfl(accc[3].x, c16, 64), g);
    const float lgr = sel4(__shfl(accc[0].y, c16, 64), __shfl(accc[1].y, c16, 64),
                           __shfl(accc[2].y, c16, 64), __shfl(accc[3].y, c16, 64), g);
    const float lb = sel4(__shfl(accc[0].z, c16, 64), __shfl(accc[1].z, c16, 64),
                          __shfl(accc[2].z, c16, 64), __shfl(accc[3].z, c16, 64), g);

    const float cr = 1.f / (1.f + expf(-lr));
    const float cg = 1.f / (1.f + expf(-lgr));
    const float cb = 1.f / (1.f + expf(-lb));
    const float gx = lgit - 1.0f;
    const float density = fmaxf(gx, 0.f) + log1pf(expf(-fabsf(gx)));

    // ---- volume rendering ----
    const float dnorm = sqrtf(dx * dx + dy * dy + dz * dz);
    float dist = (lane < 63) ? (zn - z) : 1e10f;
    dist *= dnorm;
    const float alpha = 1.0f - expf(-density * dist);
    float f = 1.0f - alpha + 1e-10f;
#pragma unroll
    for (int off = 1; off < 64; off <<= 1) {
        const float gg = __shfl_up(f, off, 64);
        if (lane >= off) f *= gg;
    }
    float T = __shfl_up(f, 1, 64);
    if (lane == 0) T = 1.0f;
    const float w = alpha * T;

    out[kOffWeights + ray * 64 + lane] = w;
    const float sr = wave_sum(w * cr);
    const float sg = wave_sum(w * cg);
    const float sb = wave_sum(w * cb);
    const float sd = wave_sum(w * z);
    const float sa = wave_sum(w);
    if (lane == 0) {
        out[ray * 3 + 0] = sr;
        out[ray * 3 + 1] = sg;
        out[ray * 3 + 2] = sb;
        out[kOffDepth + ray] = sd;
        out[kOffAcc + ray]   = sa;
    }
}

extern "C" void kernel_launch(void* const* d_in, const int* in_sizes, int n_in,
                              void* d_out, int out_size, void* d_ws, size_t ws_size,
                              hipStream_t stream) {
    const float* rays_o = (const float*)d_in[0];
    const float* rays_d = (const float*)d_in[1];
    const float* tables = (const float*)d_in[2];
    const float* Wg0 = (const float*)d_in[3];
    const float* bg0 = (const float*)d_in[4];
    const float* Wg1 = (const float*)d_in[5];
    const float* bg1 = (const float*)d_in[6];
    const float* Wd  = (const float*)d_in[7];
    const float* bd  = (const float*)d_in[8];
    const float* Wc0 = (const float*)d_in[9];
    const float* bc0 = (const float*)d_in[10];
    const float* Wc1 = (const float*)d_in[11];
    const float* bc1 = (const float*)d_in[12];
    const float* Wc2 = (const float*)d_in[13];
    const float* bc2 = (const float*)d_in[14];
    const float* Wch = (const float*)d_in[15];
    const float* bch = (const float*)d_in[16];
    float* out = (float*)d_out;
    ushort* wsp = (ushort*)d_ws;

    prep_weights<<<dim3((kWsTotal + 255) / 256), dim3(256), 0, stream>>>(
        Wg0, Wg1, Wd, Wc0, Wc1, Wc2, Wch, wsp);

    nerf_mfma_kernel<<<dim3(kNRays / 4), dim3(256), 0, stream>>>(
        rays_o, rays_d, tables, wsp,
        bg0, bg1, bd, bc0, bc1, bc2, bch, out);
}

// Round 7
// 78.857 us; speedup vs baseline: 1.0866x; 1.0866x over previous
//
#include <hip/hip_runtime.h>
#include <hip/hip_bf16.h>
#include <math.h>

typedef float  f32x4 __attribute__((ext_vector_type(4)));
typedef short  s16x8 __attribute__((ext_vector_type(8)));
typedef unsigned int u32x2 __attribute__((ext_vector_type(2)));
typedef unsigned int u32x4 __attribute__((ext_vector_type(4)));

constexpr int kNRays = 16384;
constexpr int kOffDepth   = kNRays * 3;
constexpr int kOffAcc     = kOffDepth + kNRays;
constexpr int kOffWeights = kOffAcc + kNRays;

// Pre-staged A-fragment regions in d_ws (ushort offsets)
constexpr int kWg0 = 0;      // 32x64  KT=1 MT=4 -> 2048
constexpr int kWg1 = 2048;   // 64x64  KT=2 MT=4 -> 4096
constexpr int kWd  = 6144;   // 64x16  KT=2 MT=1 -> 1024 (dperm)
constexpr int kWc0 = 7168;   // 24x64  KT=1 MT=4 -> 2048 (bc0 folded at k=24)
constexpr int kWc1 = 9216;   // 64x64  -> 4096
constexpr int kWc2 = 13312;  // 64x64  -> 4096
constexpr int kWch = 17408;  // 64x3   KT=2 MT=1 -> 1024
constexpr int kWsTotal = 18432;

__device__ __forceinline__ ushort f2bf(float x) {
    unsigned u = __float_as_uint(x);
    return (ushort)((u + 0x7FFFu + ((u >> 16) & 1u)) >> 16);
}
__device__ __forceinline__ unsigned pk2(float lo, float hi) {
    __hip_bfloat162 h = __float22bfloat162_rn(float2{lo, hi});
    return *reinterpret_cast<unsigned*>(&h);   // v_cvt_pk_bf16_f32
}
__device__ __forceinline__ float sel4(float v0, float v1, float v2, float v3, int s) {
    float a = (s & 1) ? v1 : v0;
    float b = (s & 1) ? v3 : v2;
    return (s & 2) ? b : a;
}
__device__ __forceinline__ float wave_sum(float v) {
#pragma unroll
    for (int off = 32; off > 0; off >>= 1) v += __shfl_xor(v, off, 64);
    return v;
}

// One-time weight staging: W (f32 [FIN][FOUT]) -> bf16 A-fragments in ws.
__global__ __launch_bounds__(256) void prep_weights(
    const float* __restrict__ Wg0, const float* __restrict__ Wg1,
    const float* __restrict__ Wd,  const float* __restrict__ Wc0,
    const float* __restrict__ Wc1, const float* __restrict__ Wc2,
    const float* __restrict__ Wch, const float* __restrict__ bc0,
    ushort* __restrict__ ws)
{
    const int i = blockIdx.x * 256 + threadIdx.x;
    if (i >= kWsTotal) return;
    const float* W; int FIN, FOUT, KT, base; bool dperm = false, c0bias = false;
    if (i < kWg1)      { W = Wg0; FIN = 32; FOUT = 64; KT = 1; base = kWg0; }
    else if (i < kWd)  { W = Wg1; FIN = 64; FOUT = 64; KT = 2; base = kWg1; }
    else if (i < kWc0) { W = Wd;  FIN = 64; FOUT = 16; KT = 2; base = kWd; dperm = true; }
    else if (i < kWc1) { W = Wc0; FIN = 24; FOUT = 64; KT = 1; base = kWc0; c0bias = true; }
    else if (i < kWc2) { W = Wc1; FIN = 64; FOUT = 64; KT = 2; base = kWc1; }
    else if (i < kWch) { W = Wc2; FIN = 64; FOUT = 64; KT = 2; base = kWc2; }
    else               { W = Wch; FIN = 64; FOUT = 3;  KT = 2; base = kWch; }
    const int r = i - base;
    const int e = r & 7, l = (r >> 3) & 63, t = r >> 9;
    const int kt = t % KT, mt = t / KT;
    const int k = kt * 32 + ((l >> 4) << 3) + e;
    int j = mt * 16 + (l & 15);
    if (dperm) j = (j == 15) ? 0 : j + 1;   // geo[0] -> row 15, geo[1..15] -> rows 0..14
    float w = 0.0f;
    if (k < FIN && j < FOUT) w = W[k * FOUT + j];
    if (c0bias && k == 24 && j < FOUT) w = bc0[j];  // bias row (X row 24 := 1.0)
    ws[i] = f2bf(w);
}

// Fused 64-out layer with precomputed LDS addresses (rp: 8 reads, wa: 16 writes).
template<int KT, bool HASBIAS>
__device__ __forceinline__ void layer64(ushort* __restrict__ Xw,
                                        const ushort* __restrict__ Aws,
                                        const float* __restrict__ bias,
                                        const int* rp, const int* wa,
                                        int g, int lane) {
    s16x8 B[KT][4];
#pragma unroll
    for (int kt = 0; kt < KT; ++kt)
#pragma unroll
        for (int nt = 0; nt < 4; ++nt)
            B[kt][nt] = *(const s16x8*)&Xw[rp[kt * 4 + nt]];
#pragma unroll
    for (int mt = 0; mt < 4; ++mt) {
        const s16x8 A0 = *(const s16x8*)&Aws[((mt * KT + 0) * 64 + lane) * 8];
        s16x8 A1;
        if constexpr (KT == 2) A1 = *(const s16x8*)&Aws[((mt * KT + 1) * 64 + lane) * 8];
        f32x4 b;
        if constexpr (HASBIAS) b = *(const f32x4*)(bias + mt * 16 + g * 4);
        else                   b = (f32x4){ 0.f, 0.f, 0.f, 0.f };
        f32x4 acc[4];
#pragma unroll
        for (int nt = 0; nt < 4; ++nt) {
            acc[nt] = b;
            acc[nt] = __builtin_amdgcn_mfma_f32_16x16x32_bf16(A0, B[0][nt], acc[nt], 0, 0, 0);
            if constexpr (KT == 2)
                acc[nt] = __builtin_amdgcn_mfma_f32_16x16x32_bf16(A1, B[1][nt], acc[nt], 0, 0, 0);
        }
#pragma unroll
        for (int nt = 0; nt < 4; ++nt) {
            const float x0 = fmaxf(acc[nt].x, 0.f), x1 = fmaxf(acc[nt].y, 0.f);
            const float x2 = fmaxf(acc[nt].z, 0.f), x3 = fmaxf(acc[nt].w, 0.f);
            *(u32x2*)&Xw[wa[mt * 4 + nt]] = (u32x2){ pk2(x0, x1), pk2(x2, x3) };
        }
    }
}

// Small (16-col-out) layer: MT=1, KT=2, returns acc tiles.
__device__ __forceinline__ void layer16(const ushort* __restrict__ Xw,
                                        const ushort* __restrict__ Aws,
                                        const int* rp, int lane, f32x4 acc[4]) {
    const s16x8 A0 = *(const s16x8*)&Aws[(0 * 64 + lane) * 8];
    const s16x8 A1 = *(const s16x8*)&Aws[(1 * 64 + lane) * 8];
#pragma unroll
    for (int nt = 0; nt < 4; ++nt) {
        const s16x8 B0 = *(const s16x8*)&Xw[rp[0 * 4 + nt]];
        acc[nt] = __builtin_amdgcn_mfma_f32_16x16x32_bf16(A0, B0, acc[nt], 0, 0, 0);
        const s16x8 B1 = *(const s16x8*)&Xw[rp[1 * 4 + nt]];
        acc[nt] = __builtin_amdgcn_mfma_f32_16x16x32_bf16(A1, B1, acc[nt], 0, 0, 0);
    }
}

__global__ __launch_bounds__(256, 4) void nerf_mfma_kernel(
    const float* __restrict__ rays_o, const float* __restrict__ rays_d,
    const float* __restrict__ tables, const ushort* __restrict__ ws,
    const float* __restrict__ bg0, const float* __restrict__ bg1,
    const float* __restrict__ bd,  const float* __restrict__ bc1,
    const float* __restrict__ bc2, const float* __restrict__ bch,
    float* __restrict__ out)
{
    __shared__ __align__(16) ushort Xs[4 * 4096];
    const int tid  = threadIdx.x;
    const int wid  = tid >> 6;
    const int lane = tid & 63;
    const int c16  = lane & 15;
    const int g    = lane >> 4;
    const int ray  = blockIdx.x * 4 + wid;
    ushort* Xw = Xs + wid * 4096;

    const float ox = rays_o[ray * 3 + 0], oy = rays_o[ray * 3 + 1], oz = rays_o[ray * 3 + 2];
    const float dx = rays_d[ray * 3 + 0], dy = rays_d[ray * 3 + 1], dz = rays_d[ray * 3 + 2];

    const float step = 1.0f / 63.0f;
    const float z  = 0.1f + 1.4f * ((float)lane * step);
    const float zn = 0.1f + 1.4f * ((float)(lane + 1) * step);

    // ---- precomputed LDS addresses (ushort units), reused by every layer ----
    int rp[8], wa[16];
#pragma unroll
    for (int kt = 0; kt < 2; ++kt)
#pragma unroll
        for (int nt = 0; nt < 4; ++nt)
            rp[kt * 4 + nt] = (nt * 16 + c16) * 64 + 8 * ((kt * 4 + g) ^ (c16 & 7));
#pragma unroll
    for (int mt = 0; mt < 4; ++mt)
#pragma unroll
        for (int nt = 0; nt < 4; ++nt)
            wa[mt * 4 + nt] = (nt * 16 + c16) * 64
                            + 8 * ((2 * mt + (g >> 1)) ^ (c16 & 7)) + 4 * (g & 1);

    // ---- input-layer B fragments straight from the hash gather ----
    // lane (g,c16), tile nt: sample s = nt*16+c16, levels g*4+j
    const float2* __restrict__ tb = (const float2*)tables;
    const float tc = (float)c16 * step;
    s16x8 B0f[4];
#pragma unroll
    for (int nt = 0; nt < 4; ++nt) {
        const float ts = tc + (float)nt * (16.0f / 63.0f);
        const float zs = fmaf(1.4f, ts, 0.1f);
        const float px = fmaf(dx, zs, ox), py = fmaf(dy, zs, oy), pz = fmaf(dz, zs, oz);
        u32x4 val;
#pragma unroll
        for (int j = 0; j < 4; ++j) {
            const int lv = g * 4 + j;
            const float res = (float)(32 << lv);
            const float rm1 = res - 1.0f;
            const float h = 0.5f * rm1;
            const float sx = __builtin_amdgcn_fmed3f(fmaf(px, h, h), 0.f, rm1);
            const float sy = __builtin_amdgcn_fmed3f(fmaf(py, h, h), 0.f, rm1);
            const float sz = __builtin_amdgcn_fmed3f(fmaf(pz, h, h), 0.f, rm1);
            const float idxf = fmaf(sx, res * res, fmaf(sy, res, sz));
            const float szm1 = (lv == 0) ? 32767.f : (lv == 1) ? 262143.f : 524287.f;
            const unsigned idx = (unsigned)(int)fminf(idxf, szm1);
            const float2 f2 = tb[((unsigned)lv << 19) + idx];   // 32-bit voffset, saddr base
            val[j] = pk2(f2.x, f2.y);
        }
        B0f[nt] = *(const s16x8*)&val;
    }

    // ---- g0: 32 -> 64, relu (B direct from gather) ----
#pragma unroll
    for (int mt = 0; mt < 4; ++mt) {
        const s16x8 A0 = *(const s16x8*)&ws[kWg0 + (mt * 64 + lane) * 8];
        const f32x4 b = *(const f32x4*)(bg0 + mt * 16 + g * 4);
        f32x4 acc[4];
#pragma unroll
        for (int nt = 0; nt < 4; ++nt) {
            acc[nt] = b;
            acc[nt] = __builtin_amdgcn_mfma_f32_16x16x32_bf16(A0, B0f[nt], acc[nt], 0, 0, 0);
        }
#pragma unroll
        for (int nt = 0; nt < 4; ++nt) {
            const float x0 = fmaxf(acc[nt].x, 0.f), x1 = fmaxf(acc[nt].y, 0.f);
            const float x2 = fmaxf(acc[nt].z, 0.f), x3 = fmaxf(acc[nt].w, 0.f);
            *(u32x2*)&Xw[wa[mt * 4 + nt]] = (u32x2){ pk2(x0, x1), pk2(x2, x3) };
        }
    }

    // ---- g1: 64 -> 64, relu ----
    layer64<2, true>(Xw, ws + kWg1, bg1, rp, wa, g, lane);

    // ---- d: 64 -> 16 (cols rotated; row 15 = geo[0]) ----
    f32x4 accd[4];
    {
        const float db0 = bd[g * 4 + 1];
        const float db1 = bd[g * 4 + 2];
        const float db2 = bd[g * 4 + 3];
        const int i3 = (g == 3) ? 0 : g * 4 + 4;
        const float db3 = bd[i3];
        const f32x4 b = { db0, db1, db2, db3 };
#pragma unroll
        for (int nt = 0; nt < 4; ++nt) accd[nt] = b;
    }
    layer16(Xw, ws + kWd, rp, lane, accd);
    const float lgit = sel4(__shfl(accd[0].w, 48 + c16, 64),
                            __shfl(accd[1].w, 48 + c16, 64),
                            __shfl(accd[2].w, 48 + c16, 64),
                            __shfl(accd[3].w, 48 + c16, 64), g);
    // store c_in rows 0..15 (row 15 junk, fixed below) -- wa[mt=0] pattern
#pragma unroll
    for (int nt = 0; nt < 4; ++nt)
        *(u32x2*)&Xw[wa[nt]] = (u32x2){ pk2(accd[nt].x, accd[nt].y),
                                        pk2(accd[nt].z, accd[nt].w) };
    Xw[lane * 64 + 8 * (1 ^ (lane & 7)) + 7] = 0x3F00; // row 15 := bf16(0.5)
    {   // SH rows 16..23 (per-ray uniform)
        u32x4 w = { pk2(dx, dy), pk2(dz, dx * dy), pk2(dx * dz, dy * dz),
                    pk2(dx * dx - dy * dy, 3.f * dz * dz - 1.f) };
        *(u32x4*)&Xw[lane * 64 + 8 * (2 ^ (lane & 7))] = w;
    }
    {   // rows 24..31 := {1,0,...,0}  (row 24 = 1.0 feeds the folded bc0)
        u32x4 w = { 0x00003F80u, 0u, 0u, 0u };
        *(u32x4*)&Xw[lane * 64 + 8 * (3 ^ (lane & 7))] = w;
    }

    // ---- color MLP ----
    layer64<1, false>(Xw, ws + kWc0, nullptr, rp, wa, g, lane);  // bias folded
    layer64<2, true >(Xw, ws + kWc1, bc1,     rp, wa, g, lane);
    layer64<2, true >(Xw, ws + kWc2, bc2,     rp, wa, g, lane);

    // ---- ch: 64 -> 3 ----
    f32x4 accc[4];
    {
        const float cb0 = bch[0], cb1 = bch[1], cb2 = bch[2];
        const f32x4 b = (g == 0) ? (f32x4){ cb0, cb1, cb2, 0.f } : (f32x4){ 0.f, 0.f, 0.f, 0.f };
#pragma unroll
        for (int nt = 0; nt < 4; ++nt) accc[nt] = b;
    }
    layer16(Xw, ws + kWch, rp, lane, accc);
    const float lr = sel4(__shfl(accc[0].x, c16, 64), __shfl(accc[1].x, c16, 64),
                          __shfl(accc[2].x, c16, 64), __shfl(accc[3].x, c16, 64), g);
    const float lgr = sel4(__shfl(accc[0].y, c16, 64), __shfl(accc[1].y, c16, 64),
                           __shfl(accc[2].y, c16, 64), __shfl(accc[3].y, c16, 64), g);
    const float lb = sel4(__shfl(accc[0].z, c16, 64), __shfl(accc[1].z, c16, 64),
                          __shfl(accc[2].z, c16, 64), __shfl(accc[3].z, c16, 64), g);

    const float cr = 1.f / (1.f + expf(-lr));
    const float cg = 1.f / (1.f + expf(-lgr));
    const float cb = 1.f / (1.f + expf(-lb));
    const float gx = lgit - 1.0f;
    const float density = fmaxf(gx, 0.f) + log1pf(expf(-fabsf(gx)));

    // ---- volume rendering ----
    const float dnorm = sqrtf(dx * dx + dy * dy + dz * dz);
    float dist = (lane < 63) ? (zn - z) : 1e10f;
    dist *= dnorm;
    const float alpha = 1.0f - expf(-density * dist);
    float f = 1.0f - alpha + 1e-10f;
#pragma unroll
    for (int off = 1; off < 64; off <<= 1) {
        const float gg = __shfl_up(f, off, 64);
        if (lane >= off) f *= gg;
    }
    float T = __shfl_up(f, 1, 64);
    if (lane == 0) T = 1.0f;
    const float w = alpha * T;

    out[kOffWeights + ray * 64 + lane] = w;
    const float sr = wave_sum(w * cr);
    const float sg = wave_sum(w * cg);
    const float sb = wave_sum(w * cb);
    const float sd = wave_sum(w * z);
    const float sa = wave_sum(w);
    if (lane == 0) {
        out[ray * 3 + 0] = sr;
        out[ray * 3 + 1] = sg;
        out[ray * 3 + 2] = sb;
        out[kOffDepth + ray] = sd;
        out[kOffAcc + ray]   = sa;
    }
}

extern "C" void kernel_launch(void* const* d_in, const int* in_sizes, int n_in,
                              void* d_out, int out_size, void* d_ws, size_t ws_size,
                              hipStream_t stream) {
    const float* rays_o = (const float*)d_in[0];
    const float* rays_d = (const float*)d_in[1];
    const float* tables = (const float*)d_in[2];
    const float* Wg0 = (const float*)d_in[3];
    const float* bg0 = (const float*)d_in[4];
    const float* Wg1 = (const float*)d_in[5];
    const float* bg1 = (const float*)d_in[6];
    const float* Wd  = (const float*)d_in[7];
    const float* bd  = (const float*)d_in[8];
    const float* Wc0 = (const float*)d_in[9];
    const float* bc0 = (const float*)d_in[10];
    const float* Wc1 = (const float*)d_in[11];
    const float* bc1 = (const float*)d_in[12];
    const float* Wc2 = (const float*)d_in[13];
    const float* bc2 = (const float*)d_in[14];
    const float* Wch = (const float*)d_in[15];
    const float* bch = (const float*)d_in[16];
    float* out = (float*)d_out;
    ushort* wsp = (ushort*)d_ws;

    prep_weights<<<dim3((kWsTotal + 255) / 256), dim3(256), 0, stream>>>(
        Wg0, Wg1, Wd, Wc0, Wc1, Wc2, Wch, bc0, wsp);

    nerf_mfma_kernel<<<dim3(kNRays / 4), dim3(256), 0, stream>>>(
        rays_o, rays_d, tables, wsp,
        bg0, bg1, bd, bc1, bc2, bch, out);
}